// Round 4
// baseline (4874.623 us; speedup 1.0000x reference)
//
#include <hip/hip_runtime.h>
#include <math.h>

// ExactContinuousSBM: reverse VP-SDE sampling of a Gaussian mixture.
// Round 4: single-buffered LDS (25.3 KB) + 2 barriers/step -> 4 blocks/CU;
// chunk=4 so table fragments stay register-resident (no pass2 LDS re-read);
// direct numerator accumulation n = sum e*(A - x*iv) (drops SIV/SA regs).
//
// Layout: 512 blocks x 256 threads (4 waves). Block owns 16 b's; every wave
// covers ALL 16 b's (8 d-lanes x 8 slots, 2 b per lane) and 16 of the 64 k's.
// Schedule per step: k-loop -> B1 -> cross-wave merge + EM update ->
// const-gen for j+1 -> B2.

namespace {

constexpr int BD   = 8192;
constexpr int DIMN = 32;
constexpr int KM   = 64;
constexpr int NST  = 255;
constexpr float TMINc = 1e-4f, TMAXc = 1.0f;
constexpr float BMIN = 0.1f,  BMAX = 20.0f;
constexpr float L2E = 1.4426950408889634f;   // log2(e)
constexpr float LN2 = 0.6931471805599453f;

// DPP butterfly add over the 8 d-lanes of a slot:
// 0xB1 = quad_perm xor1, 0x4E = quad_perm xor2, 0x141 = row_half_mirror.
template <int CTRL>
__device__ __forceinline__ float dpp_addf(float v) {
  int o = __builtin_amdgcn_update_dpp(0, __float_as_int(v), CTRL, 0xf, 0xf, true);
  return v + __int_as_float(o);
}
__device__ __forceinline__ float dred8(float v) {
  v = dpp_addf<0xB1>(v);
  v = dpp_addf<0x4E>(v);
  v = dpp_addf<0x141>(v);
  return v;
}

__global__ __launch_bounds__(256, 4) void sbm_kernel(
    const float* __restrict__ xin,    // [8192,32]
    const float* __restrict__ cen_g,  // [64,32]
    const float* __restrict__ std_g,  // [64,32]
    const float* __restrict__ w_g,    // [64]
    const float* __restrict__ noi,    // [255,8192,32]
    float* __restrict__ out)          // [8192,32]
{
  __shared__ __align__(16) float s_iv[KM][DIMN];   // log2e / v
  __shared__ __align__(16) float s_a [KM][DIMN];   // m * log2e / v
  __shared__ __align__(16) float s_c [KM];         // log2-domain const
  __shared__ __align__(16) float4 s_n [4][2][64];  // per-wave numerators
  __shared__ float2 s_ml[4][2][8];                 // per-wave (M, L)

  const int tid  = threadIdx.x;
  const int w    = tid >> 6;        // wave 0..3 -> k range
  const int lane = tid & 63;
  const int dc   = lane & 7;        // d-chunk (4 dims)
  const int slot = lane >> 3;       // b slot 0..7
  const int d0   = dc * 4;
  const int k0   = w * 16;
  const int b0   = blockIdx.x * 16 + slot;
  const int b1   = b0 + 8;

  // const-gen ownership: thread -> (k-row gk, 8 dims at gd)
  const int gk = tid >> 2;
  const int gd = (tid & 3) * 8;

  float cen[8], s2[8];
#pragma unroll
  for (int i = 0; i < 8; ++i) {
    cen[i] = cen_g[gk * DIMN + gd + i];
    float s = std_g[gk * DIMN + gd + i];
    s2[i] = s * s;
  }
  const float lw2 = __builtin_amdgcn_logf(w_g[gk]);   // log2(w)

  float x0[4], x1[4];
  {
    const float4 a = *reinterpret_cast<const float4*>(xin + b0 * DIMN + d0);
    const float4 b = *reinterpret_cast<const float4*>(xin + b1 * DIMN + d0);
    x0[0]=a.x; x0[1]=a.y; x0[2]=a.z; x0[3]=a.w;
    x1[0]=b.x; x1[1]=b.y; x1[2]=b.z; x1[3]=b.w;
  }

  auto gen = [&](int jj) {
    const float t  = fmaf((float)(255 - jj) * (1.0f / 255.0f), (TMAXc - TMINc), TMINc);
    const float Bt = fmaf(0.5f * (BMAX - BMIN), t * t, BMIN * t);
    const float eB  = __builtin_amdgcn_exp2f(-Bt * L2E);
    const float om  = 1.0f - eB;
    const float smB = __builtin_amdgcn_sqrtf(eB);
    float cq = 0.0f, c2 = 0.0f;
    float ivv[8], av[8];
#pragma unroll
    for (int i = 0; i < 8; ++i) {
      const float v  = fmaf(eB, s2[i], om);
      const float iv = L2E * __builtin_amdgcn_rcpf(v);
      const float m  = smB * cen[i];
      const float A  = m * iv;
      ivv[i] = iv; av[i] = A;
      cq = fmaf(m, A, cq);                 // log2e * m^2/v
      c2 += __builtin_amdgcn_logf(v);      // log2 v
    }
    *reinterpret_cast<float4*>(&s_iv[gk][gd])     = make_float4(ivv[0], ivv[1], ivv[2], ivv[3]);
    *reinterpret_cast<float4*>(&s_iv[gk][gd + 4]) = make_float4(ivv[4], ivv[5], ivv[6], ivv[7]);
    *reinterpret_cast<float4*>(&s_a [gk][gd])     = make_float4(av[0], av[1], av[2], av[3]);
    *reinterpret_cast<float4*>(&s_a [gk][gd + 4]) = make_float4(av[4], av[5], av[6], av[7]);
    float q1 = dpp_addf<0xB1>(cq); q1 = dpp_addf<0x4E>(q1);
    float q2 = dpp_addf<0xB1>(c2); q2 = dpp_addf<0x4E>(q2);
    if ((tid & 3) == 0)
      s_c[gk] = fmaf(-16.0f, q2, fmaf(-0.5f, q1, lw2));
  };

  gen(0);
  __syncthreads();

#pragma unroll 1
  for (int j = 0; j < NST; ++j) {
    // noise prefetch (consumed in the merge phase -> long latency cover)
    const float4 z0 = *reinterpret_cast<const float4*>(
        noi + ((size_t)j * BD + b0) * (size_t)DIMN + d0);
    const float4 z1 = *reinterpret_cast<const float4*>(
        noi + ((size_t)j * BD + b1) * (size_t)DIMN + d0);

    const float t  = fmaf((float)(255 - j) * (1.0f / 255.0f), (TMAXc - TMINc), TMINc);
    const float tn = fmaf((float)(254 - j) * (1.0f / 255.0f), (TMAXc - TMINc), TMINc);
    const float dt = tn - t;                 // negative
    const float bt = fmaf(BMAX - BMIN, t, BMIN);

    float h0[4], h1[4];
#pragma unroll
    for (int i = 0; i < 4; ++i) { h0[i] = -0.5f * x0[i] * x0[i]; h1[i] = -0.5f * x1[i] * x1[i]; }

    float M0 = -__builtin_inff(), M1 = -__builtin_inff();
    float L0 = 0.0f, L1 = 0.0f;
    float n0[4] = {0,0,0,0}, n1[4] = {0,0,0,0};

#pragma unroll
    for (int c = 0; c < 4; ++c) {
      const int kc = k0 + c * 4;
      const float4 cc4 = *reinterpret_cast<const float4*>(&s_c[kc]);
      const float cc[4] = {cc4.x, cc4.y, cc4.z, cc4.w};

      float4 tiv[4], ta[4];
      float p0[4], p1[4];
      float cm0 = -__builtin_inff(), cm1 = -__builtin_inff();
#pragma unroll
      for (int kk = 0; kk < 4; ++kk) {
        tiv[kk] = *reinterpret_cast<const float4*>(&s_iv[kc + kk][d0]);
        ta[kk]  = *reinterpret_cast<const float4*>(&s_a [kc + kk][d0]);
        float pa = h0[0] * tiv[kk].x;
        pa = fmaf(x0[0], ta[kk].x, pa);
        pa = fmaf(h0[1], tiv[kk].y, pa);
        pa = fmaf(x0[1], ta[kk].y, pa);
        pa = fmaf(h0[2], tiv[kk].z, pa);
        pa = fmaf(x0[2], ta[kk].z, pa);
        pa = fmaf(h0[3], tiv[kk].w, pa);
        pa = fmaf(x0[3], ta[kk].w, pa);
        float pb = h1[0] * tiv[kk].x;
        pb = fmaf(x1[0], ta[kk].x, pb);
        pb = fmaf(h1[1], tiv[kk].y, pb);
        pb = fmaf(x1[1], ta[kk].y, pb);
        pb = fmaf(h1[2], tiv[kk].z, pb);
        pb = fmaf(x1[2], ta[kk].z, pb);
        pb = fmaf(h1[3], tiv[kk].w, pb);
        pb = fmaf(x1[3], ta[kk].w, pb);
        pa = dred8(pa) + cc[kk];
        pb = dred8(pb) + cc[kk];
        p0[kk] = pa; p1[kk] = pb;
        cm0 = fmaxf(cm0, pa); cm1 = fmaxf(cm1, pb);
      }
      // fold chunk into running state: one rescale per chunk (n only)
      const float nM0 = fmaxf(M0, cm0), nM1 = fmaxf(M1, cm1);
      const float al0 = __builtin_amdgcn_exp2f(M0 - nM0);   // 0 on first chunk
      const float al1 = __builtin_amdgcn_exp2f(M1 - nM1);
      M0 = nM0; M1 = nM1;
      L0 *= al0; L1 *= al1;
#pragma unroll
      for (int i = 0; i < 4; ++i) { n0[i] *= al0; n1[i] *= al1; }
#pragma unroll
      for (int kk = 0; kk < 4; ++kk) {
        const float e0 = __builtin_amdgcn_exp2f(p0[kk] - M0);
        const float e1 = __builtin_amdgcn_exp2f(p1[kk] - M1);
        L0 += e0; L1 += e1;
#pragma unroll
        for (int i = 0; i < 4; ++i) {
          const float* tv = &tiv[kk].x;
          const float* tA = &ta[kk].x;
          const float u0 = fmaf(-x0[i], tv[i], tA[i]);   // A - x*iv
          const float u1 = fmaf(-x1[i], tv[i], tA[i]);
          n0[i] = fmaf(e0, u0, n0[i]);
          n1[i] = fmaf(e1, u1, n1[i]);
        }
      }
    }

    // publish per-wave partials
    s_n[w][0][lane] = make_float4(n0[0], n0[1], n0[2], n0[3]);
    s_n[w][1][lane] = make_float4(n1[0], n1[1], n1[2], n1[3]);
    if (dc == 0) {
      s_ml[w][0][slot] = make_float2(M0, L0);
      s_ml[w][1][slot] = make_float2(M1, L1);
    }
    __syncthreads();   // B1: k-loop table reads + s_n/s_ml writes complete

    // ---- cross-wave merge + Euler-Maruyama update ----
    const float cA  = fmaf(-0.5f * bt, dt, 1.0f);
    const float cb0 = (-bt * dt) * LN2;
    const float sq  = __builtin_amdgcn_sqrtf(bt) * __builtin_amdgcn_sqrtf(-dt);
    const int w1 = w ^ 1, w2 = w ^ 2, w3 = w ^ 3;

    {  // b0
      const float2 mA = s_ml[w1][0][slot];
      const float2 mB = s_ml[w2][0][slot];
      const float2 mC = s_ml[w3][0][slot];
      const float Gm = fmaxf(fmaxf(M0, mA.x), fmaxf(mB.x, mC.x));
      const float ss = __builtin_amdgcn_exp2f(M0 - Gm);
      const float sA = __builtin_amdgcn_exp2f(mA.x - Gm);
      const float sB = __builtin_amdgcn_exp2f(mB.x - Gm);
      const float sC = __builtin_amdgcn_exp2f(mC.x - Gm);
      float Lt = ss * L0;
      Lt = fmaf(sA, mA.y, Lt); Lt = fmaf(sB, mB.y, Lt); Lt = fmaf(sC, mC.y, Lt);
      const float4 nA = s_n[w1][0][lane];
      const float4 nB = s_n[w2][0][lane];
      const float4 nC = s_n[w3][0][lane];
      float nu[4] = {ss * n0[0], ss * n0[1], ss * n0[2], ss * n0[3]};
      nu[0] = fmaf(sA, nA.x, nu[0]); nu[1] = fmaf(sA, nA.y, nu[1]);
      nu[2] = fmaf(sA, nA.z, nu[2]); nu[3] = fmaf(sA, nA.w, nu[3]);
      nu[0] = fmaf(sB, nB.x, nu[0]); nu[1] = fmaf(sB, nB.y, nu[1]);
      nu[2] = fmaf(sB, nB.z, nu[2]); nu[3] = fmaf(sB, nB.w, nu[3]);
      nu[0] = fmaf(sC, nC.x, nu[0]); nu[1] = fmaf(sC, nC.y, nu[1]);
      nu[2] = fmaf(sC, nC.z, nu[2]); nu[3] = fmaf(sC, nC.w, nu[3]);
      const float cb2 = cb0 * __builtin_amdgcn_rcpf(Lt);
      const float zc[4] = {z0.x, z0.y, z0.z, z0.w};
#pragma unroll
      for (int i = 0; i < 4; ++i)
        x0[i] = fmaf(cb2, nu[i], fmaf(cA, x0[i], sq * zc[i]));
    }
    {  // b1
      const float2 mA = s_ml[w1][1][slot];
      const float2 mB = s_ml[w2][1][slot];
      const float2 mC = s_ml[w3][1][slot];
      const float Gm = fmaxf(fmaxf(M1, mA.x), fmaxf(mB.x, mC.x));
      const float ss = __builtin_amdgcn_exp2f(M1 - Gm);
      const float sA = __builtin_amdgcn_exp2f(mA.x - Gm);
      const float sB = __builtin_amdgcn_exp2f(mB.x - Gm);
      const float sC = __builtin_amdgcn_exp2f(mC.x - Gm);
      float Lt = ss * L1;
      Lt = fmaf(sA, mA.y, Lt); Lt = fmaf(sB, mB.y, Lt); Lt = fmaf(sC, mC.y, Lt);
      const float4 nA = s_n[w1][1][lane];
      const float4 nB = s_n[w2][1][lane];
      const float4 nC = s_n[w3][1][lane];
      float nu[4] = {ss * n1[0], ss * n1[1], ss * n1[2], ss * n1[3]};
      nu[0] = fmaf(sA, nA.x, nu[0]); nu[1] = fmaf(sA, nA.y, nu[1]);
      nu[2] = fmaf(sA, nA.z, nu[2]); nu[3] = fmaf(sA, nA.w, nu[3]);
      nu[0] = fmaf(sB, nB.x, nu[0]); nu[1] = fmaf(sB, nB.y, nu[1]);
      nu[2] = fmaf(sB, nB.z, nu[2]); nu[3] = fmaf(sB, nB.w, nu[3]);
      nu[0] = fmaf(sC, nC.x, nu[0]); nu[1] = fmaf(sC, nC.y, nu[1]);
      nu[2] = fmaf(sC, nC.z, nu[2]); nu[3] = fmaf(sC, nC.w, nu[3]);
      const float cb2 = cb0 * __builtin_amdgcn_rcpf(Lt);
      const float zc[4] = {z1.x, z1.y, z1.z, z1.w};
#pragma unroll
      for (int i = 0; i < 4; ++i)
        x1[i] = fmaf(cb2, nu[i], fmaf(cA, x1[i], sq * zc[i]));
    }

    // const-gen for the next step into the (single) table buffer.
    // Safe: B1 guaranteed every wave finished reading this step's tables.
    if (j + 1 < NST) gen(j + 1);
    __syncthreads();   // B2: tables for j+1 ready; s_n merge-reads done
  }

  if (w == 0) {   // x replicated across waves; one writer
    *reinterpret_cast<float4*>(out + b0 * DIMN + d0) = make_float4(x0[0], x0[1], x0[2], x0[3]);
    *reinterpret_cast<float4*>(out + b1 * DIMN + d0) = make_float4(x1[0], x1[1], x1[2], x1[3]);
  }
}

}  // namespace

extern "C" void kernel_launch(void* const* d_in, const int* in_sizes, int n_in,
                              void* d_out, int out_size, void* d_ws, size_t ws_size,
                              hipStream_t stream) {
  const float* x_init  = (const float*)d_in[0];
  const float* centers = (const float*)d_in[1];
  const float* stds    = (const float*)d_in[2];
  const float* weights = (const float*)d_in[3];
  const float* noise   = (const float*)d_in[4];
  float* out = (float*)d_out;

  sbm_kernel<<<dim3(512), dim3(256), 0, stream>>>(x_init, centers, stds, weights,
                                                  noise, out);
}